// Round 8
// baseline (2162.005 us; speedup 1.0000x reference)
//
#include <hip/hip_runtime.h>
#include <math.h>

#define NROW 16384   // B*T
#define DIN  768
#define DD   512
#define KCB  8192
#define NBLK 64
#define QELEMS 8388608
#define TOK_OFF 8388608
#define LOSS_OFF 8404992
#define PERP_OFF 8404993
#define LSTR 134     // LDS row stride (floats): writes 2-way, reads conflict-free at BK=32

typedef unsigned long long ull;

__device__ inline unsigned int fsort(float s) {
    unsigned int u = __float_as_uint(s);
    return (u & 0x80000000u) ? ~u : (u | 0x80000000u);
}

// ---------- numpy pairwise-sum emulation: sum of squares of 512 contiguous f32 ----------
__device__ inline float leaf128_sq(const float* __restrict__ p) {
    float m[16];
    #pragma unroll
    for (int l = 0; l < 16; l++) {
        float j0 = __fmul_rn(p[l +   0], p[l +   0]);
        float j1 = __fmul_rn(p[l +  16], p[l +  16]);
        float j2 = __fmul_rn(p[l +  32], p[l +  32]);
        float j3 = __fmul_rn(p[l +  48], p[l +  48]);
        float j4 = __fmul_rn(p[l +  64], p[l +  64]);
        float j5 = __fmul_rn(p[l +  80], p[l +  80]);
        float j6 = __fmul_rn(p[l +  96], p[l +  96]);
        float j7 = __fmul_rn(p[l + 112], p[l + 112]);
        m[l] = __fadd_rn(__fadd_rn(__fadd_rn(j0, j1), __fadd_rn(j2, j3)),
                         __fadd_rn(__fadd_rn(j4, j5), __fadd_rn(j6, j7)));
    }
    #pragma unroll
    for (int s = 8; s >= 1; s >>= 1)
        #pragma unroll
        for (int l = 0; l < 8; l++)
            if (l < s) m[l] = __fadd_rn(m[l], m[l + s]);
    return m[0];
}
__device__ inline float np_sum512_sq(const float* __restrict__ v) {
    float L0 = leaf128_sq(v);
    float L1 = leaf128_sq(v + 128);
    float L2 = leaf128_sq(v + 256);
    float L3 = leaf128_sq(v + 384);
    return __fadd_rn(__fadd_rn(L0, L1), __fadd_rn(L2, L3));
}

// ---------- K1: emulated einsum projection  F = einsum(x,W) + b ----------
// Bit-exact numpy einsum chain: per (n,j), acc = fadd(acc, fmul(x,w)) over f ascending.
// BK=32 staging (half the barriers of BK=16).
__global__ __launch_bounds__(256) void femu_kernel(const float* __restrict__ X, const float* __restrict__ W,
                                                   const float* __restrict__ Bv, float* __restrict__ F) {
    __shared__ float xsT[32][LSTR];
    __shared__ float wsh[32][LSTR];
    const int tid = threadIdx.x;
    const int nt = tid >> 4, jt = tid & 15;
    const int n0 = blockIdx.y * 128, j0 = blockIdx.x * 128;
    float acc[8][8];
    #pragma unroll
    for (int i = 0; i < 8; i++)
        #pragma unroll
        for (int q = 0; q < 8; q++) acc[i][q] = 0.0f;

    for (int fc = 0; fc < DIN; fc += 32) {
        #pragma unroll
        for (int i = 0; i < 4; i++) {
            int idx = tid + i * 256;
            int row = idx >> 3, kc = (idx & 7) * 4;
            float4 v = *(const float4*)(X + (size_t)(n0 + row) * DIN + fc + kc);
            xsT[kc + 0][row] = v.x; xsT[kc + 1][row] = v.y; xsT[kc + 2][row] = v.z; xsT[kc + 3][row] = v.w;
        }
        #pragma unroll
        for (int i = 0; i < 4; i++) {
            int idx = tid + i * 256;
            int r = idx >> 5, c4 = (idx & 31) * 4;
            *(float4*)&wsh[r][c4] = *(const float4*)(W + (size_t)(fc + r) * DD + j0 + c4);
        }
        __syncthreads();
        #pragma unroll 4
        for (int f = 0; f < 32; f++) {
            float4 x0 = *(float4*)&xsT[f][nt * 8];
            float4 x1 = *(float4*)&xsT[f][nt * 8 + 4];
            float4 w0 = *(float4*)&wsh[f][jt * 4];
            float4 w1 = *(float4*)&wsh[f][64 + jt * 4];
            float xv[8] = {x0.x, x0.y, x0.z, x0.w, x1.x, x1.y, x1.z, x1.w};
            float wv[8] = {w0.x, w0.y, w0.z, w0.w, w1.x, w1.y, w1.z, w1.w};
            #pragma unroll
            for (int i = 0; i < 8; i++)
                #pragma unroll
                for (int q = 0; q < 8; q++)
                    acc[i][q] = __fadd_rn(acc[i][q], __fmul_rn(xv[i], wv[q]));
        }
        __syncthreads();
    }
    #pragma unroll
    for (int i = 0; i < 8; i++) {
        int n = n0 + nt * 8 + i;
        #pragma unroll
        for (int h = 0; h < 2; h++) {
            int col = j0 + h * 64 + jt * 4;
            float4 o;
            o.x = __fadd_rn(acc[i][h * 4 + 0], Bv[col + 0]);
            o.y = __fadd_rn(acc[i][h * 4 + 1], Bv[col + 1]);
            o.z = __fadd_rn(acc[i][h * 4 + 2], Bv[col + 2]);
            o.w = __fadd_rn(acc[i][h * 4 + 3], Bv[col + 3]);
            *(float4*)(F + (size_t)n * DD + col) = o;
        }
    }
}

// ---------- K2: np.sum(x*x, axis=1) for F rows (A) and codebook rows (B) ----------
__global__ __launch_bounds__(256) void norms_kernel(const float* __restrict__ F, const float* __restrict__ CB,
                                                    float* __restrict__ Av, float* __restrict__ Bn) {
    int t = blockIdx.x * 256 + threadIdx.x;
    if (t < NROW) {
        Av[t] = np_sum512_sq(F + (size_t)t * DD);
    } else {
        int k = t - NROW;
        if (k < KCB) Bn[k] = np_sum512_sq(CB + (size_t)k * DD);
    }
}

// ---------- K3: emulated dists + first-index argmin per (row, col-block) ----------
// 128x128 tile, 8x8/thread, BK=32 (half the barrier pairs), split-col B-frag.
// Bit-exact single-accumulator ascending-k fmaf chain; dist = f32(f32(A+B) - f32(2*C)).
__global__ __launch_bounds__(256) void score_kernel(const float* __restrict__ F, const float* __restrict__ CB,
                                                    const float* __restrict__ Av, const float* __restrict__ Bn,
                                                    ull* __restrict__ keys) {
    __shared__ float At[32][LSTR];
    __shared__ float Bt[32][LSTR];
    const int tid = threadIdx.x;
    const int tr = tid >> 4, tc = tid & 15;
    const int m0 = blockIdx.y * 128, n0 = blockIdx.x * 128;
    float acc[8][8];
    #pragma unroll
    for (int i = 0; i < 8; i++)
        #pragma unroll
        for (int j = 0; j < 8; j++) acc[i][j] = 0.0f;

    for (int kt = 0; kt < DD; kt += 32) {
        #pragma unroll
        for (int i = 0; i < 4; i++) {
            int idx = tid + i * 256;
            int row = idx >> 3, kc = (idx & 7) * 4;
            float4 v = *(const float4*)(F + (size_t)(m0 + row) * DD + kt + kc);
            At[kc + 0][row] = v.x; At[kc + 1][row] = v.y; At[kc + 2][row] = v.z; At[kc + 3][row] = v.w;
        }
        #pragma unroll
        for (int i = 0; i < 4; i++) {
            int idx = tid + i * 256;
            int col = idx >> 3, kc = (idx & 7) * 4;
            float4 v = *(const float4*)(CB + (size_t)(n0 + col) * DD + kt + kc);
            Bt[kc + 0][col] = v.x; Bt[kc + 1][col] = v.y; Bt[kc + 2][col] = v.z; Bt[kc + 3][col] = v.w;
        }
        __syncthreads();
        #pragma unroll 4
        for (int kk = 0; kk < 32; kk++) {
            float4 a0 = *(float4*)&At[kk][tr * 8];
            float4 a1 = *(float4*)&At[kk][tr * 8 + 4];
            float4 b0 = *(float4*)&Bt[kk][tc * 4];
            float4 b1 = *(float4*)&Bt[kk][64 + tc * 4];
            float a[8] = {a0.x, a0.y, a0.z, a0.w, a1.x, a1.y, a1.z, a1.w};
            float b[8] = {b0.x, b0.y, b0.z, b0.w, b1.x, b1.y, b1.z, b1.w};
            #pragma unroll
            for (int i = 0; i < 8; i++)
                #pragma unroll
                for (int j = 0; j < 8; j++)
                    acc[i][j] = fmaf(a[i], b[j], acc[i][j]);
        }
        __syncthreads();
    }
    // epilogue: dist keys + first-index argmin within this 128-col block
    float Bk[8];
    int cols[8];
    #pragma unroll
    for (int j = 0; j < 8; j++) {
        cols[j] = n0 + (j < 4 ? tc * 4 + j : 64 + tc * 4 + (j - 4));
        Bk[j] = Bn[cols[j]];
    }
    #pragma unroll
    for (int i = 0; i < 8; i++) {
        int row = m0 + tr * 8 + i;
        float Ai = Av[row];
        ull mk = ~0ull;
        #pragma unroll
        for (int j = 0; j < 8; j++) {
            float t1 = __fadd_rn(Ai, Bk[j]);
            float t2 = __fsub_rn(t1, __fmul_rn(2.0f, acc[i][j]));
            ull key = ((ull)fsort(t2) << 32) | (unsigned int)cols[j];
            mk = mk < key ? mk : key;
        }
        #pragma unroll
        for (int off = 1; off < 16; off <<= 1) {
            ull o = __shfl_xor(mk, off, 16);
            mk = mk < o ? mk : o;
        }
        if (tc == 0) keys[(size_t)row * NBLK + blockIdx.x] = mk;
    }
}

// ---------- K4: global first-index argmin per row ----------
__global__ __launch_bounds__(256) void reduce_kernel(const ull* __restrict__ keys, int* __restrict__ tokens) {
    int w = threadIdx.x >> 6, lane = threadIdx.x & 63;
    int row = blockIdx.x * 4 + w;
    ull mk = keys[(size_t)row * NBLK + lane];
    #pragma unroll
    for (int off = 1; off < 64; off <<= 1) {
        ull o = __shfl_xor(mk, off, 64);
        mk = mk < o ? mk : o;
    }
    if (lane == 0) tokens[row] = (int)(mk & 0xFFFFFFFFull);
}

// ---------- K5: gather + loss + histogram + token write ----------
__global__ __launch_bounds__(256) void epilogue_kernel(const float* __restrict__ CB, const int* __restrict__ tokens,
                                                       unsigned int* __restrict__ counts, float* __restrict__ lossp,
                                                       float* out) {
    int w = threadIdx.x >> 6, lane = threadIdx.x & 63;
    int row = blockIdx.x * 4 + w;
    int idx = tokens[row];
    const float4* c4 = (const float4*)(CB + (size_t)idx * DD);
    float4* q4 = (float4*)(out + (size_t)row * DD);
    float4 c0 = c4[lane], c1 = c4[lane + 64];
    float4 f0 = q4[lane], f1 = q4[lane + 64];
    float s = (c0.x - f0.x) * (c0.x - f0.x) + (c0.y - f0.y) * (c0.y - f0.y)
            + (c0.z - f0.z) * (c0.z - f0.z) + (c0.w - f0.w) * (c0.w - f0.w)
            + (c1.x - f1.x) * (c1.x - f1.x) + (c1.y - f1.y) * (c1.y - f1.y)
            + (c1.z - f1.z) * (c1.z - f1.z) + (c1.w - f1.w) * (c1.w - f1.w);
    q4[lane] = c0;
    q4[lane + 64] = c1;
    #pragma unroll
    for (int off = 32; off; off >>= 1) s += __shfl_xor(s, off, 64);
    if (lane == 0) {
        atomicAdd(lossp, s);
        atomicAdd(&counts[idx], 1u);
        out[TOK_OFF + row] = (float)idx;
    }
}

// ---------- K6: scalars ----------
__global__ __launch_bounds__(256) void finalize_kernel(const unsigned int* __restrict__ counts,
                                                       const float* __restrict__ lossp, float* out) {
    __shared__ double red[256];
    int t = threadIdx.x;
    double h = 0.0;
    for (int n = t; n < KCB; n += 256) {
        unsigned int c = counts[n];
        if (c) {
            double p = (double)c / (double)NROW;
            h += p * log(p + 1e-10);
        }
    }
    red[t] = h;
    __syncthreads();
    for (int off = 128; off; off >>= 1) {
        if (t < off) red[t] += red[t + off];
        __syncthreads();
    }
    if (t == 0) {
        out[LOSS_OFF] = (float)(1.25 * ((double)lossp[0] / (double)QELEMS));
        out[PERP_OFF] = (float)exp(-red[0]);
    }
}

extern "C" void kernel_launch(void* const* d_in, const int* in_sizes, int n_in,
                              void* d_out, int out_size, void* d_ws, size_t ws_size,
                              hipStream_t stream) {
    const float* X  = (const float*)d_in[0];
    const float* W  = (const float*)d_in[1];
    const float* Bv = (const float*)d_in[2];
    const float* CB = (const float*)d_in[3];
    float* out = (float*)d_out;
    float* F = out; // emulated projection staged in the quantized region; overwritten by epilogue

    char* ws = (char*)d_ws;
    ull* keys = (ull*)ws;                                    // 16384*64*8 = 8.4 MB
    int* tokens = (int*)(keys + (size_t)NROW * NBLK);        // 16384 i32
    unsigned int* counts = (unsigned int*)(tokens + NROW);   // 8192 u32
    float* lossp = (float*)(counts + KCB);                   // 1
    float* Aemu = lossp + 1;                                 // 16384 f32
    float* Bemu = Aemu + NROW;                               // 8192 f32

    size_t off_zero = (char*)counts - ws;
    hipMemsetAsync(ws + off_zero, 0, KCB * 4 + 4, stream);   // counts + loss

    femu_kernel<<<dim3(DD / 128, NROW / 128), 256, 0, stream>>>(X, W, Bv, F);
    norms_kernel<<<(NROW + KCB) / 256, 256, 0, stream>>>(F, CB, Aemu, Bemu);
    score_kernel<<<dim3(NBLK, NROW / 128), 256, 0, stream>>>(F, CB, Aemu, Bemu, keys);
    reduce_kernel<<<NROW / 4, 256, 0, stream>>>(keys, tokens);
    epilogue_kernel<<<NROW / 4, 256, 0, stream>>>(CB, tokens, counts, lossp, out);
    finalize_kernel<<<1, 256, 0, stream>>>(counts, lossp, out);
}

// Round 9
// 2051.349 us; speedup vs baseline: 1.0539x; 1.0539x over previous
//
#include <hip/hip_runtime.h>
#include <math.h>

#define NROW 16384   // B*T
#define DIN  768
#define DD   512
#define KCB  8192
#define NBLK 32                 // KCB/256 column blocks in score GEMM
#define QELEMS 8388608
#define TOK_OFF 8388608
#define LOSS_OFF 8404992
#define PERP_OFF 8404993

typedef unsigned long long ull;

__device__ inline unsigned int fsort(float s) {
    unsigned int u = __float_as_uint(s);
    return (u & 0x80000000u) ? ~u : (u | 0x80000000u);
}

// ---------- numpy pairwise-sum emulation: sum of squares of 512 contiguous f32 ----------
__device__ inline float leaf128_sq(const float* __restrict__ p) {
    float m[16];
    #pragma unroll
    for (int l = 0; l < 16; l++) {
        float j0 = __fmul_rn(p[l +   0], p[l +   0]);
        float j1 = __fmul_rn(p[l +  16], p[l +  16]);
        float j2 = __fmul_rn(p[l +  32], p[l +  32]);
        float j3 = __fmul_rn(p[l +  48], p[l +  48]);
        float j4 = __fmul_rn(p[l +  64], p[l +  64]);
        float j5 = __fmul_rn(p[l +  80], p[l +  80]);
        float j6 = __fmul_rn(p[l +  96], p[l +  96]);
        float j7 = __fmul_rn(p[l + 112], p[l + 112]);
        m[l] = __fadd_rn(__fadd_rn(__fadd_rn(j0, j1), __fadd_rn(j2, j3)),
                         __fadd_rn(__fadd_rn(j4, j5), __fadd_rn(j6, j7)));
    }
    #pragma unroll
    for (int s = 8; s >= 1; s >>= 1)
        #pragma unroll
        for (int l = 0; l < 8; l++)
            if (l < s) m[l] = __fadd_rn(m[l], m[l + s]);
    return m[0];
}
__device__ inline float np_sum512_sq(const float* __restrict__ v) {
    float L0 = leaf128_sq(v);
    float L1 = leaf128_sq(v + 128);
    float L2 = leaf128_sq(v + 256);
    float L3 = leaf128_sq(v + 384);
    return __fadd_rn(__fadd_rn(L0, L1), __fadd_rn(L2, L3));
}

// ---------- K1: emulated einsum projection  F = einsum(x,W) + b  (R7-proven) ----------
__global__ __launch_bounds__(256) void femu_kernel(const float* __restrict__ X, const float* __restrict__ W,
                                                   const float* __restrict__ Bv, float* __restrict__ F) {
    __shared__ float xsT[16][132];
    __shared__ float wsh[16][132];
    const int tid = threadIdx.x;
    const int nt = tid >> 4, jt = tid & 15;
    const int n0 = blockIdx.y * 128, j0 = blockIdx.x * 128;
    float acc[8][8];
    #pragma unroll
    for (int i = 0; i < 8; i++)
        #pragma unroll
        for (int q = 0; q < 8; q++) acc[i][q] = 0.0f;

    for (int fc = 0; fc < DIN; fc += 16) {
        #pragma unroll
        for (int i = 0; i < 2; i++) {
            int idx = tid + i * 256;
            int row = idx >> 2, kc = (idx & 3) * 4;
            float4 v = *(const float4*)(X + (size_t)(n0 + row) * DIN + fc + kc);
            xsT[kc + 0][row] = v.x; xsT[kc + 1][row] = v.y; xsT[kc + 2][row] = v.z; xsT[kc + 3][row] = v.w;
        }
        #pragma unroll
        for (int i = 0; i < 2; i++) {
            int idx = tid + i * 256;
            int r = idx >> 5, c4 = (idx & 31) * 4;
            *(float4*)&wsh[r][c4] = *(const float4*)(W + (size_t)(fc + r) * DD + j0 + c4);
        }
        __syncthreads();
        #pragma unroll 4
        for (int f = 0; f < 16; f++) {
            float4 x0 = *(float4*)&xsT[f][nt * 8];
            float4 x1 = *(float4*)&xsT[f][nt * 8 + 4];
            float4 w0 = *(float4*)&wsh[f][jt * 4];
            float4 w1 = *(float4*)&wsh[f][64 + jt * 4];
            float xv[8] = {x0.x, x0.y, x0.z, x0.w, x1.x, x1.y, x1.z, x1.w};
            float wv[8] = {w0.x, w0.y, w0.z, w0.w, w1.x, w1.y, w1.z, w1.w};
            #pragma unroll
            for (int i = 0; i < 8; i++)
                #pragma unroll
                for (int q = 0; q < 8; q++)
                    acc[i][q] = __fadd_rn(acc[i][q], __fmul_rn(xv[i], wv[q]));
        }
        __syncthreads();
    }
    #pragma unroll
    for (int i = 0; i < 8; i++) {
        int n = n0 + nt * 8 + i;
        #pragma unroll
        for (int h = 0; h < 2; h++) {
            int col = j0 + h * 64 + jt * 4;
            float4 o;
            o.x = __fadd_rn(acc[i][h * 4 + 0], Bv[col + 0]);
            o.y = __fadd_rn(acc[i][h * 4 + 1], Bv[col + 1]);
            o.z = __fadd_rn(acc[i][h * 4 + 2], Bv[col + 2]);
            o.w = __fadd_rn(acc[i][h * 4 + 3], Bv[col + 3]);
            *(float4*)(F + (size_t)n * DD + col) = o;
        }
    }
}

// ---------- K2: np.sum(x*x, axis=1) for F rows (A) and codebook rows (B) ----------
__global__ __launch_bounds__(256) void norms_kernel(const float* __restrict__ F, const float* __restrict__ CB,
                                                    float* __restrict__ Av, float* __restrict__ Bn) {
    int t = blockIdx.x * 256 + threadIdx.x;
    if (t < NROW) {
        Av[t] = np_sum512_sq(F + (size_t)t * DD);
    } else {
        int k = t - NROW;
        if (k < KCB) Bn[k] = np_sum512_sq(CB + (size_t)k * DD);
    }
}

// ---------- K3: emulated dists + first-index argmin per (row, col-block) ----------
// 128x256 tile, 8x16/thread (21.3 FMA per b128 read -> LDS off the critical path).
// Bit-exact single-accumulator ascending-k fmaf chain; dist = f32(f32(A+B) - f32(2*C)).
__global__ __launch_bounds__(256) void score_kernel(const float* __restrict__ F, const float* __restrict__ CB,
                                                    const float* __restrict__ Av, const float* __restrict__ Bn,
                                                    ull* __restrict__ keys) {
    __shared__ float At[16][132];
    __shared__ float Bt[16][260];
    const int tid = threadIdx.x;
    const int tr = tid >> 4, tc = tid & 15;
    const int m0 = blockIdx.y * 128, n0 = blockIdx.x * 256;
    float acc[8][16];
    #pragma unroll
    for (int i = 0; i < 8; i++)
        #pragma unroll
        for (int j = 0; j < 16; j++) acc[i][j] = 0.0f;

    for (int kt = 0; kt < DD; kt += 16) {
        #pragma unroll
        for (int i = 0; i < 2; i++) {
            int idx = tid + i * 256;
            int row = idx >> 2, kc = (idx & 3) * 4;
            float4 v = *(const float4*)(F + (size_t)(m0 + row) * DD + kt + kc);
            At[kc + 0][row] = v.x; At[kc + 1][row] = v.y; At[kc + 2][row] = v.z; At[kc + 3][row] = v.w;
        }
        #pragma unroll
        for (int i = 0; i < 4; i++) {
            int idx = tid + i * 256;
            int col = idx >> 2, kc = (idx & 3) * 4;
            float4 v = *(const float4*)(CB + (size_t)(n0 + col) * DD + kt + kc);
            Bt[kc + 0][col] = v.x; Bt[kc + 1][col] = v.y; Bt[kc + 2][col] = v.z; Bt[kc + 3][col] = v.w;
        }
        __syncthreads();
        #pragma unroll 2
        for (int kk = 0; kk < 16; kk++) {
            float4 a0 = *(float4*)&At[kk][tr * 8];
            float4 a1 = *(float4*)&At[kk][tr * 8 + 4];
            float4 b0 = *(float4*)&Bt[kk][tc * 4];
            float4 b1 = *(float4*)&Bt[kk][64 + tc * 4];
            float4 b2 = *(float4*)&Bt[kk][128 + tc * 4];
            float4 b3 = *(float4*)&Bt[kk][192 + tc * 4];
            float a[8] = {a0.x, a0.y, a0.z, a0.w, a1.x, a1.y, a1.z, a1.w};
            float b[16] = {b0.x, b0.y, b0.z, b0.w, b1.x, b1.y, b1.z, b1.w,
                           b2.x, b2.y, b2.z, b2.w, b3.x, b3.y, b3.z, b3.w};
            #pragma unroll
            for (int i = 0; i < 8; i++)
                #pragma unroll
                for (int j = 0; j < 16; j++)
                    acc[i][j] = fmaf(a[i], b[j], acc[i][j]);
        }
        __syncthreads();
    }
    // epilogue: dist keys + first-index argmin within this 256-col block
    float Bk[16];
    int cols[16];
    #pragma unroll
    for (int j = 0; j < 16; j++) {
        cols[j] = n0 + (j >> 2) * 64 + tc * 4 + (j & 3);
        Bk[j] = Bn[cols[j]];
    }
    #pragma unroll
    for (int i = 0; i < 8; i++) {
        int row = m0 + tr * 8 + i;
        float Ai = Av[row];
        ull mk = ~0ull;
        #pragma unroll
        for (int j = 0; j < 16; j++) {
            float t1 = __fadd_rn(Ai, Bk[j]);
            float t2 = __fsub_rn(t1, __fmul_rn(2.0f, acc[i][j]));
            ull key = ((ull)fsort(t2) << 32) | (unsigned int)cols[j];
            mk = mk < key ? mk : key;
        }
        #pragma unroll
        for (int off = 1; off < 16; off <<= 1) {
            ull o = __shfl_xor(mk, off, 16);
            mk = mk < o ? mk : o;
        }
        if (tc == 0) keys[(size_t)row * NBLK + blockIdx.x] = mk;
    }
}

// ---------- K4: global first-index argmin per row (32 keys/row, 8 rows/block) ----------
__global__ __launch_bounds__(256) void reduce_kernel(const ull* __restrict__ keys, int* __restrict__ tokens) {
    int w = threadIdx.x >> 5, lane = threadIdx.x & 31;
    int row = blockIdx.x * 8 + w;
    ull mk = keys[(size_t)row * NBLK + lane];
    #pragma unroll
    for (int off = 1; off < 32; off <<= 1) {
        ull o = __shfl_xor(mk, off, 32);
        mk = mk < o ? mk : o;
    }
    if (lane == 0) tokens[row] = (int)(mk & 0xFFFFFFFFull);
}

// ---------- K5: gather + loss + histogram + token write ----------
__global__ __launch_bounds__(256) void epilogue_kernel(const float* __restrict__ CB, const int* __restrict__ tokens,
                                                       unsigned int* __restrict__ counts, float* __restrict__ lossp,
                                                       float* out) {
    int w = threadIdx.x >> 6, lane = threadIdx.x & 63;
    int row = blockIdx.x * 4 + w;
    int idx = tokens[row];
    const float4* c4 = (const float4*)(CB + (size_t)idx * DD);
    float4* q4 = (float4*)(out + (size_t)row * DD);
    float4 c0 = c4[lane], c1 = c4[lane + 64];
    float4 f0 = q4[lane], f1 = q4[lane + 64];
    float s = (c0.x - f0.x) * (c0.x - f0.x) + (c0.y - f0.y) * (c0.y - f0.y)
            + (c0.z - f0.z) * (c0.z - f0.z) + (c0.w - f0.w) * (c0.w - f0.w)
            + (c1.x - f1.x) * (c1.x - f1.x) + (c1.y - f1.y) * (c1.y - f1.y)
            + (c1.z - f1.z) * (c1.z - f1.z) + (c1.w - f1.w) * (c1.w - f1.w);
    q4[lane] = c0;
    q4[lane + 64] = c1;
    #pragma unroll
    for (int off = 32; off; off >>= 1) s += __shfl_xor(s, off, 64);
    if (lane == 0) {
        atomicAdd(lossp, s);
        atomicAdd(&counts[idx], 1u);
        out[TOK_OFF + row] = (float)idx;
    }
}

// ---------- K6: scalars ----------
__global__ __launch_bounds__(256) void finalize_kernel(const unsigned int* __restrict__ counts,
                                                       const float* __restrict__ lossp, float* out) {
    __shared__ double red[256];
    int t = threadIdx.x;
    double h = 0.0;
    for (int n = t; n < KCB; n += 256) {
        unsigned int c = counts[n];
        if (c) {
            double p = (double)c / (double)NROW;
            h += p * log(p + 1e-10);
        }
    }
    red[t] = h;
    __syncthreads();
    for (int off = 128; off; off >>= 1) {
        if (t < off) red[t] += red[t + off];
        __syncthreads();
    }
    if (t == 0) {
        out[LOSS_OFF] = (float)(1.25 * ((double)lossp[0] / (double)QELEMS));
        out[PERP_OFF] = (float)exp(-red[0]);
    }
}

extern "C" void kernel_launch(void* const* d_in, const int* in_sizes, int n_in,
                              void* d_out, int out_size, void* d_ws, size_t ws_size,
                              hipStream_t stream) {
    const float* X  = (const float*)d_in[0];
    const float* W  = (const float*)d_in[1];
    const float* Bv = (const float*)d_in[2];
    const float* CB = (const float*)d_in[3];
    float* out = (float*)d_out;
    float* F = out; // emulated projection staged in the quantized region; overwritten by epilogue

    char* ws = (char*)d_ws;
    ull* keys = (ull*)ws;                                    // 16384*32*8 = 4.2 MB
    int* tokens = (int*)(keys + (size_t)NROW * NBLK);        // 16384 i32
    unsigned int* counts = (unsigned int*)(tokens + NROW);   // 8192 u32
    float* lossp = (float*)(counts + KCB);                   // 1
    float* Aemu = lossp + 1;                                 // 16384 f32
    float* Bemu = Aemu + NROW;                               // 8192 f32

    size_t off_zero = (char*)counts - ws;
    hipMemsetAsync(ws + off_zero, 0, KCB * 4 + 4, stream);   // counts + loss

    femu_kernel<<<dim3(DD / 128, NROW / 128), 256, 0, stream>>>(X, W, Bv, F);
    norms_kernel<<<(NROW + KCB) / 256, 256, 0, stream>>>(F, CB, Aemu, Bemu);
    score_kernel<<<dim3(NBLK, NROW / 128), 256, 0, stream>>>(F, CB, Aemu, Bemu, keys);
    reduce_kernel<<<NROW / 8, 256, 0, stream>>>(keys, tokens);
    epilogue_kernel<<<NROW / 4, 256, 0, stream>>>(CB, tokens, counts, lossp, out);
    finalize_kernel<<<1, 256, 0, stream>>>(counts, lossp, out);
}